// Round 12
// baseline (7574.838 us; speedup 1.0000x reference)
//
#include <hip/hip_runtime.h>
#include <cstdint>

typedef float f32x4 __attribute__((ext_vector_type(4)));

// Problem constants
static constexpr int Hdim = 1024;
static constexpr int Vdim = 128;
static constexpr int Bdim = 64;
static constexpr int Sdim = 512;

// Persistent kernel geometry
static constexpr int NB   = 8;     // batches per block (= per cluster)
static constexpr int NI   = 32;    // output columns per block
static constexpr int KCH  = 32;    // k elements per thread chunk
static constexpr int NBLK = 256;   // total blocks (1 per CU)
static constexpr int BPC  = 32;    // blocks per cluster
static constexpr int NCL  = 8;     // clusters (NCL*NB = 64 batches)

// ---------------- prep: pack U^T ----------------
// Up[s][k][il] = U[s*32+il][k]  (block s streams a contiguous [1024][32] slice)
__global__ void __launch_bounds__(256) pack_u_kernel(const float* __restrict__ U,
                                                     float* __restrict__ Up) {
  __shared__ float tile[32][257];
  const int s  = blockIdx.x;        // 0..31 (column-slice)
  const int k0 = blockIdx.y * 256;  // 0,256,512,768
  const int t  = threadIdx.x;
  #pragma unroll
  for (int r = 0; r < 32; ++r)
    tile[r][t] = U[(size_t)(s * 32 + r) * Hdim + k0 + t];
  __syncthreads();
  const size_t base = ((size_t)s * Hdim + k0) * 32;
  #pragma unroll
  for (int r2 = 0; r2 < 32; ++r2) {
    int g = r2 * 256 + t;           // g = k_rel*32 + il
    Up[base + g] = tile[g & 31][g >> 5];
  }
}

// ---------------- prep: W [1024][128] -> Wt [128][1024] ----------------
__global__ void transpose_w_kernel(const float* __restrict__ in, float* __restrict__ out) {
  __shared__ float tile[32][33];
  const int bx = blockIdx.x * 32;   // col base (vocab)
  const int by = blockIdx.y * 32;   // row base (hidden)
  const int tx = threadIdx.x, ty = threadIdx.y;  // 32 x 8
  #pragma unroll
  for (int dy = 0; dy < 32; dy += 8)
    tile[ty + dy][tx] = in[(size_t)(by + ty + dy) * Vdim + bx + tx];
  __syncthreads();
  #pragma unroll
  for (int dy = 0; dy < 32; dy += 8)
    out[(size_t)(bx + ty + dy) * Hdim + by + tx] = tile[tx][ty + dy];
}

// ---------------- persistent recurrence + fused logits ----------------
// Registers-only h path: thread (kp,b) owns h[b][kp*32..+31] (8 x f32x4),
// loaded straight from IF (sc0 sc1) -- no LDS staging, no bank conflicts.
// Co-residency (plain-launch fallback): LDS ~4.5 KB, grid 256 = 1 block/CU,
// so all blocks resident regardless of dispatch order.
// U locality automatic: XCD = blk%8, s = blk&31 => s%8 == XCD, 4 slices/XCD.
__global__ void __launch_bounds__(256, 1) rnn_persist_kernel(
    const float* __restrict__ Up,   // [32][1024][32] packed U^T
    const float* __restrict__ Wt,   // [V][H]
    const int*   __restrict__ X,    // [B][S]
    const float* __restrict__ lw,   // [V][H]
    const float* __restrict__ lb,   // [V]
    float* __restrict__ h0,
    float* __restrict__ h1,
    unsigned int* __restrict__ flags, // [NCL][BPC] step-tags
    float* __restrict__ out)        // [B][S][V] (logits; softmaxed later)
{
  __shared__ float part[4][NB][NI];       // per-wave recurrence partials (4 KB)
  __shared__ float partv[4][NB][4];       // per-wave logit partials

  const int tid  = threadIdx.x;
  const int blk  = blockIdx.x;
  const int cl   = blk >> 5;              // cluster 0..7
  const int s    = blk & 31;              // column-slice 0..31
  const int i0   = s * NI;                // global column base
  const int bg0  = cl * NB;               // global batch base
  const int kp   = tid >> 3;              // 0..31
  const int b    = tid & 7;               // 0..7
  const int w    = tid >> 6;              // wave 0..3
  const int lane = tid & 63;
  const float* Ublk = Up + (size_t)s * Hdim * NI;

  f32x4 h4[8];                            // h_t[bg0+b][kp*32 .. +31]

  auto load_h = [&](int t) {
    if (t == 0) {
      #pragma unroll
      for (int r = 0; r < 8; ++r) h4[r] = (f32x4){0.f, 0.f, 0.f, 0.f};
    } else {
      const float* hc = (t & 1) ? h1 : h0;
      const float* p = hc + (size_t)(bg0 + b) * Hdim + kp * KCH;
      // 16B system-scope loads: coherent at IF, bypass L1/L2. Contiguous
      // 128B chunk per thread; early-clobber so outputs never alias addrs.
      asm volatile(
          "global_load_dwordx4 %0, %8, off sc0 sc1\n\t"
          "global_load_dwordx4 %1, %8, off offset:16 sc0 sc1\n\t"
          "global_load_dwordx4 %2, %8, off offset:32 sc0 sc1\n\t"
          "global_load_dwordx4 %3, %8, off offset:48 sc0 sc1\n\t"
          "global_load_dwordx4 %4, %8, off offset:64 sc0 sc1\n\t"
          "global_load_dwordx4 %5, %8, off offset:80 sc0 sc1\n\t"
          "global_load_dwordx4 %6, %8, off offset:96 sc0 sc1\n\t"
          "global_load_dwordx4 %7, %8, off offset:112 sc0 sc1\n\t"
          "s_waitcnt vmcnt(0)"
          : "=&v"(h4[0]), "=&v"(h4[1]), "=&v"(h4[2]), "=&v"(h4[3]),
            "=&v"(h4[4]), "=&v"(h4[5]), "=&v"(h4[6]), "=&v"(h4[7])
          : "v"(p)
          : "memory");
    }
  };

  auto logits_partial = [&]() {  // h_t in regs -> partv (4 vocab rows 4s..4s+3)
    float a0 = 0.f, a1 = 0.f, a2 = 0.f, a3 = 0.f;
    const f32x4* lw0 = (const f32x4*)(lw + (size_t)(4 * s)     * Hdim + kp * KCH);
    const f32x4* lw1 = (const f32x4*)(lw + (size_t)(4 * s + 1) * Hdim + kp * KCH);
    const f32x4* lw2 = (const f32x4*)(lw + (size_t)(4 * s + 2) * Hdim + kp * KCH);
    const f32x4* lw3 = (const f32x4*)(lw + (size_t)(4 * s + 3) * Hdim + kp * KCH);
    #pragma unroll
    for (int j4 = 0; j4 < 8; ++j4) {
      const f32x4 hv = h4[j4];
      const f32x4 q0 = lw0[j4], q1 = lw1[j4], q2 = lw2[j4], q3 = lw3[j4];
      #pragma unroll
      for (int e = 0; e < 4; ++e) {
        a0 += hv[e] * q0[e]; a1 += hv[e] * q1[e];
        a2 += hv[e] * q2[e]; a3 += hv[e] * q3[e];
      }
    }
    #pragma unroll
    for (int d = 8; d < 64; d <<= 1) {
      a0 += __shfl_xor(a0, d, 64); a1 += __shfl_xor(a1, d, 64);
      a2 += __shfl_xor(a2, d, 64); a3 += __shfl_xor(a3, d, 64);
    }
    if ((lane & 56) == 0)
      *((f32x4*)&partv[w][b][0]) = (f32x4){a0, a1, a2, a3};
  };

  auto logits_combine = [&](int tt) {  // partv -> out[:, tt, 4s..4s+3]
    if (tid >= 128 && tid < 128 + 4 * NB) {
      const int q = tid - 128;
      const int bb = q >> 2, vv = q & 3;
      float lv = partv[0][bb][vv] + partv[1][bb][vv] + partv[2][bb][vv] + partv[3][bb][vv];
      lv += lb[4 * s + vv];
      out[((size_t)(bg0 + bb) * Sdim + tt) * Vdim + 4 * s + vv] = lv;
    }
  };

  for (int t = 0; t < Sdim; ++t) {
    load_h(t);

    // ---- recurrence: acc[i] = sum over own k-chunk of U^T[k][i]*h[k] ----
    {
      float acc[NI];
      #pragma unroll
      for (int i = 0; i < NI; ++i) acc[i] = 0.f;
      const f32x4* ub = (const f32x4*)(Ublk + (size_t)kp * KCH * NI);
      #pragma unroll
      for (int j4 = 0; j4 < 8; ++j4) {
        #pragma unroll
        for (int e = 0; e < 4; ++e) {
          const float hv = h4[j4][e];
          const f32x4* u = ub + (size_t)(j4 * 4 + e) * (NI / 4);
          #pragma unroll
          for (int q = 0; q < NI / 4; ++q) {
            const f32x4 uq = u[q];
            acc[q * 4 + 0] += uq[0] * hv;
            acc[q * 4 + 1] += uq[1] * hv;
            acc[q * 4 + 2] += uq[2] * hv;
            acc[q * 4 + 3] += uq[3] * hv;
          }
        }
      }
      #pragma unroll
      for (int i = 0; i < NI; ++i) {
        acc[i] += __shfl_xor(acc[i], 8, 64);
        acc[i] += __shfl_xor(acc[i], 16, 64);
        acc[i] += __shfl_xor(acc[i], 32, 64);
      }
      if ((lane & 56) == 0) {
        #pragma unroll
        for (int i = 0; i < NI; i += 4)
          *((f32x4*)&part[w][b][i]) = (f32x4){acc[i], acc[i + 1], acc[i + 2], acc[i + 3]};
      }
    }
    __syncthreads();

    // ---- h_{t+1} update + IF store issue (all 256 threads; NB*NI = 256) ----
    {
      const int b2 = tid >> 5, i2 = tid & 31;
      float v = part[0][b2][i2] + part[1][b2][i2] + part[2][b2][i2] + part[3][b2][i2];
      const int x = X[(bg0 + b2) * Sdim + t];
      v += Wt[(size_t)x * Hdim + i0 + i2];
      v = tanhf(v);
      float* hn = (t & 1) ? h0 : h1;
      __hip_atomic_store(&hn[(size_t)(bg0 + b2) * Hdim + i0 + i2], v,
                         __ATOMIC_RELAXED, __HIP_MEMORY_SCOPE_SYSTEM);
    }

    // ---- logits for step t-1 from registers (hides h-store flight) ----
    if (t > 0) logits_partial();

    // ---- drain own h-stores to IF, then publish step-tag ----
    asm volatile("s_waitcnt vmcnt(0)" ::: "memory");
    __syncthreads();                       // all waves' h-stores IF-complete
    if (tid == 0)
      __hip_atomic_store(&flags[cl * BPC + s], (unsigned)(t + 1),
                         __ATOMIC_RELAXED, __HIP_MEMORY_SCOPE_SYSTEM);
    if (t > 0) logits_combine(t - 1);      // plain cached writes; gates no one

    // ---- wave-parallel poll: lane l watches flag[cl][l & 31] ----
    if (tid < 64) {
      const unsigned int tag = (unsigned)(t + 1);
      unsigned int* f = &flags[cl * BPC + (tid & (BPC - 1))];
      while (true) {
        unsigned int fv = __hip_atomic_load(f, __ATOMIC_RELAXED, __HIP_MEMORY_SCOPE_SYSTEM);
        if (__all((int)(fv >= tag))) break;
        __builtin_amdgcn_s_sleep(1);
      }
    }
    __syncthreads();
  }

  // ---- epilogue: logits for the final state h_S ----
  load_h(Sdim);
  logits_partial();
  __syncthreads();
  logits_combine(Sdim - 1);
}

// ---------------- in-place softmax over last dim (128) ----------------
__global__ void __launch_bounds__(256) softmax_kernel(float* __restrict__ out) {
  const int row = blockIdx.x * 4 + (threadIdx.x >> 6);  // one wave per row
  const int l = threadIdx.x & 63;
  float* rp = out + (size_t)row * Vdim;
  float2 v = *((const float2*)&rp[l * 2]);
  float m = fmaxf(v.x, v.y);
  #pragma unroll
  for (int d = 1; d < 64; d <<= 1) m = fmaxf(m, __shfl_xor(m, d, 64));
  float e0 = expf(v.x - m), e1 = expf(v.y - m);
  float ss = e0 + e1;
  #pragma unroll
  for (int d = 1; d < 64; d <<= 1) ss += __shfl_xor(ss, d, 64);
  const float inv = 1.f / ss;
  *((float2*)&rp[l * 2]) = make_float2(e0 * inv, e1 * inv);
}

extern "C" void kernel_launch(void* const* d_in, const int* in_sizes, int n_in,
                              void* d_out, int out_size, void* d_ws, size_t ws_size,
                              hipStream_t stream) {
  const int*   X  = (const int*)d_in[0];
  const float* U  = (const float*)d_in[1];
  const float* W  = (const float*)d_in[2];
  const float* lw = (const float*)d_in[3];
  const float* lb = (const float*)d_in[4];
  float* out = (float*)d_out;

  // workspace layout (floats): Up[1M] | Wt[128K] | h0[64K] | h1[64K] | flags
  float* Up = (float*)d_ws;
  float* Wt = Up + (size_t)1024 * 1024;
  float* h0 = Wt + (size_t)128 * 1024;
  float* h1 = h0 + (size_t)64 * 1024;
  unsigned int* flags = (unsigned int*)(h1 + (size_t)64 * 1024);
  const size_t need = ((size_t)1024 * 1024 + 128 * 1024 + 2 * 64 * 1024) * 4 + NCL * BPC * 4;
  if (ws_size < need) return;

  // flags must be zero each call (tags are per-launch monotonic; the graph
  // replays this memset, so re-validation after timing stays correct).
  hipMemsetAsync(flags, 0, (size_t)NCL * BPC * sizeof(unsigned int), stream);

  hipLaunchKernelGGL(pack_u_kernel, dim3(32, 4), dim3(256), 0, stream, U, Up);
  hipLaunchKernelGGL(transpose_w_kernel, dim3(4, 32), dim3(32, 8), 0, stream, W, Wt);

  void* args[] = {(void*)&Up, (void*)&Wt, (void*)&X, (void*)&lw, (void*)&lb,
                  (void*)&h0, (void*)&h1, (void*)&flags, (void*)&out};
  hipError_t ce = hipLaunchCooperativeKernel((void*)rnn_persist_kernel,
                                             dim3(NBLK), dim3(256), args, 0, stream);
  if (ce != hipSuccess) {
    // Silent-coop-failure fallback: plain launch. All 256 blocks are
    // co-resident by resource arithmetic (see kernel comment), so the
    // flag barrier is safe without the cooperative API.
    hipLaunchKernelGGL(rnn_persist_kernel, dim3(NBLK), dim3(256), 0, stream,
                       Up, Wt, X, lw, lb, h0, h1, flags, out);
  }

  hipLaunchKernelGGL(softmax_kernel, dim3((Bdim * Sdim) / 4), dim3(256), 0, stream, out);
}

// Round 14
// 6503.259 us; speedup vs baseline: 1.1648x; 1.1648x over previous
//
#include <hip/hip_runtime.h>
#include <cstdint>

typedef float f32x4 __attribute__((ext_vector_type(4)));
typedef unsigned int u32x4 __attribute__((ext_vector_type(4)));

// Problem constants
static constexpr int Hdim = 1024;
static constexpr int Vdim = 128;
static constexpr int Bdim = 64;
static constexpr int Sdim = 512;

// Persistent kernel geometry
static constexpr int NB   = 8;     // batches per block (= per cluster)
static constexpr int NI   = 32;    // output columns per block
static constexpr int KCH  = 32;    // k elements per thread chunk
static constexpr int SL   = 1028;  // LDS h row stride in floats
static constexpr int NBLK = 256;   // total blocks (1 per CU)
static constexpr int BPC  = 32;    // blocks per cluster
static constexpr int NCL  = 8;     // clusters (NCL*NB = 64 batches)

// ---------------- prep: pack U^T ----------------
// Up[s][k][il] = U[s*32+il][k]  (block s streams a contiguous [1024][32] slice)
__global__ void __launch_bounds__(256) pack_u_kernel(const float* __restrict__ U,
                                                     float* __restrict__ Up) {
  __shared__ float tile[32][257];
  const int s  = blockIdx.x;        // 0..31 (column-slice)
  const int k0 = blockIdx.y * 256;  // 0,256,512,768
  const int t  = threadIdx.x;
  #pragma unroll
  for (int r = 0; r < 32; ++r)
    tile[r][t] = U[(size_t)(s * 32 + r) * Hdim + k0 + t];
  __syncthreads();
  const size_t base = ((size_t)s * Hdim + k0) * 32;
  #pragma unroll
  for (int r2 = 0; r2 < 32; ++r2) {
    int g = r2 * 256 + t;           // g = k_rel*32 + il
    Up[base + g] = tile[g & 31][g >> 5];
  }
}

// ---------------- prep: W [1024][128] -> Wt [128][1024] ----------------
__global__ void transpose_w_kernel(const float* __restrict__ in, float* __restrict__ out) {
  __shared__ float tile[32][33];
  const int bx = blockIdx.x * 32;   // col base (vocab)
  const int by = blockIdx.y * 32;   // row base (hidden)
  const int tx = threadIdx.x, ty = threadIdx.y;  // 32 x 8
  #pragma unroll
  for (int dy = 0; dy < 32; dy += 8)
    tile[ty + dy][tx] = in[(size_t)(by + ty + dy) * Vdim + bx + tx];
  __syncthreads();
  #pragma unroll
  for (int dy = 0; dy < 32; dy += 8)
    out[(size_t)(bx + ty + dy) * Hdim + by + tx] = tile[tx][ty + dy];
}

// ---------------- persistent recurrence + fused logits ----------------
// Barrier-free tagged-pair dataflow: h is exchanged as 8B {f32 value, u32
// step-tag} packets through the IF (sc0 sc1). A consumer proceeds when all
// its 32 pairs carry tag == t; an 8B aligned store is single-copy atomic, so
// no flags, no vmcnt drain, no publish, no cluster barrier. Deadlock-free by
// induction (producers depend only on earlier tags; buffer-reuse distance 2
// prevents overwrite-before-read). Equality check self-corrects stale data.
// Co-residency (plain-launch fallback): ~37 KB LDS -> 4 blocks/CU capacity,
// grid 256 = 1/CU; even uneven placement fits, dataflow needs no ordering.
__global__ void __launch_bounds__(256, 1) rnn_persist_kernel(
    const float* __restrict__ Up,   // [32][1024][32] packed U^T
    const float* __restrict__ Wt,   // [V][H]
    const int*   __restrict__ X,    // [B][S]
    const float* __restrict__ lw,   // [V][H]
    const float* __restrict__ lb,   // [V]
    unsigned int* __restrict__ hp0, // [B][H] {val,tag} pairs, buffer 0
    unsigned int* __restrict__ hp1, // [B][H] {val,tag} pairs, buffer 1
    float* __restrict__ out)        // [B][S][V] (logits; softmaxed later)
{
  __shared__ float hsm[NB * SL];          // staged h_t slice (8 rows)
  __shared__ float part[4][NB][NI];       // per-wave recurrence partials
  __shared__ float partv[4][NB][4];       // per-wave logit partials

  const int tid  = threadIdx.x;
  const int blk  = blockIdx.x;
  const int cl   = blk >> 5;              // cluster 0..7
  const int s    = blk & 31;              // column-slice 0..31
  const int i0   = s * NI;                // global column base
  const int bg0  = cl * NB;               // global batch base
  const int kp   = tid >> 3;              // 0..31
  const int b    = tid & 7;               // 0..7
  const int w    = tid >> 6;              // wave 0..3
  const int lane = tid & 63;
  const float* Ublk = Up + (size_t)s * Hdim * NI;

  auto stage_h = [&](int t) {
    if (t == 0) {
      const f32x4 z = (f32x4){0.f, 0.f, 0.f, 0.f};
      #pragma unroll
      for (int r = 0; r < NB; ++r)
        *((f32x4*)&hsm[r * SL + tid * 4]) = z;
      return;
    }
    const unsigned int* hc = (t & 1) ? hp1 : hp0;
    // Row r pairs for columns tid*4 .. tid*4+3 (4 pairs = 32B = 2 dwordx4).
    const unsigned int* a0 = hc + ((size_t)(bg0 + 0) * Hdim + tid * 4) * 2;
    const unsigned int* a1 = hc + ((size_t)(bg0 + 1) * Hdim + tid * 4) * 2;
    const unsigned int* a2 = hc + ((size_t)(bg0 + 2) * Hdim + tid * 4) * 2;
    const unsigned int* a3 = hc + ((size_t)(bg0 + 3) * Hdim + tid * 4) * 2;
    const unsigned int* a4 = hc + ((size_t)(bg0 + 4) * Hdim + tid * 4) * 2;
    const unsigned int* a5 = hc + ((size_t)(bg0 + 5) * Hdim + tid * 4) * 2;
    const unsigned int* a6 = hc + ((size_t)(bg0 + 6) * Hdim + tid * 4) * 2;
    const unsigned int* a7 = hc + ((size_t)(bg0 + 7) * Hdim + tid * 4) * 2;
    const unsigned int tag = (unsigned int)t;
    u32x4 q[16];
    while (true) {
      asm volatile(
          "global_load_dwordx4 %0, %16, off sc0 sc1\n\t"
          "global_load_dwordx4 %1, %16, off offset:16 sc0 sc1\n\t"
          "global_load_dwordx4 %2, %17, off sc0 sc1\n\t"
          "global_load_dwordx4 %3, %17, off offset:16 sc0 sc1\n\t"
          "global_load_dwordx4 %4, %18, off sc0 sc1\n\t"
          "global_load_dwordx4 %5, %18, off offset:16 sc0 sc1\n\t"
          "global_load_dwordx4 %6, %19, off sc0 sc1\n\t"
          "global_load_dwordx4 %7, %19, off offset:16 sc0 sc1\n\t"
          "global_load_dwordx4 %8, %20, off sc0 sc1\n\t"
          "global_load_dwordx4 %9, %20, off offset:16 sc0 sc1\n\t"
          "global_load_dwordx4 %10, %21, off sc0 sc1\n\t"
          "global_load_dwordx4 %11, %21, off offset:16 sc0 sc1\n\t"
          "global_load_dwordx4 %12, %22, off sc0 sc1\n\t"
          "global_load_dwordx4 %13, %22, off offset:16 sc0 sc1\n\t"
          "global_load_dwordx4 %14, %23, off sc0 sc1\n\t"
          "global_load_dwordx4 %15, %23, off offset:16 sc0 sc1\n\t"
          "s_waitcnt vmcnt(0)"
          : "=&v"(q[0]), "=&v"(q[1]), "=&v"(q[2]), "=&v"(q[3]),
            "=&v"(q[4]), "=&v"(q[5]), "=&v"(q[6]), "=&v"(q[7]),
            "=&v"(q[8]), "=&v"(q[9]), "=&v"(q[10]), "=&v"(q[11]),
            "=&v"(q[12]), "=&v"(q[13]), "=&v"(q[14]), "=&v"(q[15])
          : "v"(a0), "v"(a1), "v"(a2), "v"(a3), "v"(a4), "v"(a5), "v"(a6), "v"(a7)
          : "memory");
      unsigned int okb = 1u;
      #pragma unroll
      for (int i = 0; i < 16; ++i)
        okb &= (unsigned)(q[i][1] == tag) & (unsigned)(q[i][3] == tag);
      if (okb) break;
      __builtin_amdgcn_s_sleep(1);
    }
    #pragma unroll
    for (int r = 0; r < NB; ++r)
      *((f32x4*)&hsm[r * SL + tid * 4]) = (f32x4){
          __uint_as_float(q[2 * r][0]), __uint_as_float(q[2 * r][2]),
          __uint_as_float(q[2 * r + 1][0]), __uint_as_float(q[2 * r + 1][2])};
  };

  auto logits_partial = [&]() {  // h_t in hsm -> partv (4 vocab rows 4s..4s+3)
    float a0 = 0.f, a1 = 0.f, a2 = 0.f, a3 = 0.f;
    const f32x4* lw0 = (const f32x4*)(lw + (size_t)(4 * s)     * Hdim + kp * KCH);
    const f32x4* lw1 = (const f32x4*)(lw + (size_t)(4 * s + 1) * Hdim + kp * KCH);
    const f32x4* lw2 = (const f32x4*)(lw + (size_t)(4 * s + 2) * Hdim + kp * KCH);
    const f32x4* lw3 = (const f32x4*)(lw + (size_t)(4 * s + 3) * Hdim + kp * KCH);
    const f32x4* hr4 = (const f32x4*)&hsm[b * SL + kp * KCH];
    #pragma unroll
    for (int j = 0; j < KCH / 4; ++j) {
      int jj = (j + kp) & (KCH / 4 - 1);
      f32x4 hv = hr4[jj];
      f32x4 q0 = lw0[jj], q1 = lw1[jj], q2 = lw2[jj], q3 = lw3[jj];
      #pragma unroll
      for (int e = 0; e < 4; ++e) {
        a0 += hv[e] * q0[e]; a1 += hv[e] * q1[e];
        a2 += hv[e] * q2[e]; a3 += hv[e] * q3[e];
      }
    }
    #pragma unroll
    for (int d = 8; d < 64; d <<= 1) {
      a0 += __shfl_xor(a0, d, 64); a1 += __shfl_xor(a1, d, 64);
      a2 += __shfl_xor(a2, d, 64); a3 += __shfl_xor(a3, d, 64);
    }
    if ((lane & 56) == 0)
      *((f32x4*)&partv[w][b][0]) = (f32x4){a0, a1, a2, a3};
  };

  auto logits_combine = [&](int tt) {  // partv -> out[:, tt, 4s..4s+3]
    if (tid >= 128 && tid < 128 + 4 * NB) {
      const int q = tid - 128;
      const int bb = q >> 2, vv = q & 3;
      float lv = partv[0][bb][vv] + partv[1][bb][vv] + partv[2][bb][vv] + partv[3][bb][vv];
      lv += lb[4 * s + vv];
      out[((size_t)(bg0 + bb) * Sdim + tt) * Vdim + 4 * s + vv] = lv;
    }
  };

  for (int t = 0; t < Sdim; ++t) {
    stage_h(t);
    __syncthreads();

    // ---- recurrence: acc[i] = sum over this thread's k-chunk of U^T[k][i]*h[k] ----
    {
      float acc[NI];
      #pragma unroll
      for (int i = 0; i < NI; ++i) acc[i] = 0.f;
      const float* hr = &hsm[b * SL + kp * KCH];
      const f32x4* ub = (const f32x4*)(Ublk + (size_t)kp * KCH * NI);
      #pragma unroll 4
      for (int j = 0; j < KCH; ++j) {
        int jj = (j + kp) & (KCH - 1);
        float hv = hr[jj];
        const f32x4* u = ub + (size_t)jj * (NI / 4);
        #pragma unroll
        for (int q = 0; q < NI / 4; ++q) {
          const f32x4 uq = u[q];
          acc[q * 4 + 0] += uq[0] * hv;
          acc[q * 4 + 1] += uq[1] * hv;
          acc[q * 4 + 2] += uq[2] * hv;
          acc[q * 4 + 3] += uq[3] * hv;
        }
      }
      #pragma unroll
      for (int i = 0; i < NI; ++i) {
        acc[i] += __shfl_xor(acc[i], 8, 64);
        acc[i] += __shfl_xor(acc[i], 16, 64);
        acc[i] += __shfl_xor(acc[i], 32, 64);
      }
      if ((lane & 56) == 0) {
        #pragma unroll
        for (int i = 0; i < NI; i += 4)
          *((f32x4*)&part[w][b][i]) = (f32x4){acc[i], acc[i + 1], acc[i + 2], acc[i + 3]};
      }
    }
    __syncthreads();

    // ---- h_{t+1} update: store {value, tag=t+1} pair, fire-and-forget ----
    {
      const int b2 = tid >> 5, i2 = tid & 31;
      float v = part[0][b2][i2] + part[1][b2][i2] + part[2][b2][i2] + part[3][b2][i2];
      const int x = X[(bg0 + b2) * Sdim + t];
      v += Wt[(size_t)x * Hdim + i0 + i2];
      v = tanhf(v);
      unsigned int* hn = (t & 1) ? hp0 : hp1;
      unsigned int* hp = hn + ((size_t)(bg0 + b2) * Hdim + i0 + i2) * 2;
      unsigned long long pkt = ((unsigned long long)(unsigned)(t + 1) << 32) |
                               (unsigned long long)__float_as_uint(v);
      asm volatile("global_store_dwordx2 %0, %1, off sc0 sc1"
                   :: "v"(hp), "v"(pkt) : "memory");
    }

    // ---- logits for step t-1 from hsm (hides store flight; no barrier) ----
    if (t > 0) logits_partial();
    __syncthreads();
    if (t > 0) logits_combine(t - 1);
  }

  // ---- epilogue: logits for the final state h_S ----
  stage_h(Sdim);
  __syncthreads();
  logits_partial();
  __syncthreads();
  logits_combine(Sdim - 1);
}

// ---------------- in-place softmax over last dim (128) ----------------
__global__ void __launch_bounds__(256) softmax_kernel(float* __restrict__ out) {
  const int row = blockIdx.x * 4 + (threadIdx.x >> 6);  // one wave per row
  const int l = threadIdx.x & 63;
  float* rp = out + (size_t)row * Vdim;
  float2 v = *((const float2*)&rp[l * 2]);
  float m = fmaxf(v.x, v.y);
  #pragma unroll
  for (int d = 1; d < 64; d <<= 1) m = fmaxf(m, __shfl_xor(m, d, 64));
  float e0 = expf(v.x - m), e1 = expf(v.y - m);
  float ss = e0 + e1;
  #pragma unroll
  for (int d = 1; d < 64; d <<= 1) ss += __shfl_xor(ss, d, 64);
  const float inv = 1.f / ss;
  *((float2*)&rp[l * 2]) = make_float2(e0 * inv, e1 * inv);
}

extern "C" void kernel_launch(void* const* d_in, const int* in_sizes, int n_in,
                              void* d_out, int out_size, void* d_ws, size_t ws_size,
                              hipStream_t stream) {
  const int*   X  = (const int*)d_in[0];
  const float* U  = (const float*)d_in[1];
  const float* W  = (const float*)d_in[2];
  const float* lw = (const float*)d_in[3];
  const float* lb = (const float*)d_in[4];
  float* out = (float*)d_out;

  // workspace: Up[1M f32] | Wt[128K f32] | hp0[128K u32] | hp1[128K u32]
  float* Up = (float*)d_ws;
  float* Wt = Up + (size_t)1024 * 1024;
  unsigned int* hp0 = (unsigned int*)(Wt + (size_t)128 * 1024);
  unsigned int* hp1 = hp0 + (size_t)Bdim * Hdim * 2;
  const size_t need = ((size_t)1024 * 1024 + 128 * 1024) * 4 +
                      (size_t)2 * Bdim * Hdim * 2 * 4;
  if (ws_size < need) return;

  // Zero both pair buffers每 launch (tags must start below 1; graph replays
  // this memset so timing replays and re-validation stay deterministic).
  hipMemsetAsync(hp0, 0, (size_t)2 * Bdim * Hdim * 2 * sizeof(unsigned int), stream);

  hipLaunchKernelGGL(pack_u_kernel, dim3(32, 4), dim3(256), 0, stream, U, Up);
  hipLaunchKernelGGL(transpose_w_kernel, dim3(4, 32), dim3(32, 8), 0, stream, W, Wt);

  void* args[] = {(void*)&Up, (void*)&Wt, (void*)&X, (void*)&lw, (void*)&lb,
                  (void*)&hp0, (void*)&hp1, (void*)&out};
  hipError_t ce = hipLaunchCooperativeKernel((void*)rnn_persist_kernel,
                                             dim3(NBLK), dim3(256), args, 0, stream);
  if (ce != hipSuccess) {
    // Dataflow kernel needs no launch-order guarantees; plain launch is safe
    // (1 block/CU by resources; protocol is pure producer->consumer tags).
    hipLaunchKernelGGL(rnn_persist_kernel, dim3(NBLK), dim3(256), 0, stream,
                       Up, Wt, X, lw, lb, hp0, hp1, out);
  }

  hipLaunchKernelGGL(softmax_kernel, dim3((Bdim * Sdim) / 4), dim3(256), 0, stream, out);
}

// Round 15
// 6244.357 us; speedup vs baseline: 1.2131x; 1.0415x over previous
//
#include <hip/hip_runtime.h>
#include <cstdint>

typedef float f32x4 __attribute__((ext_vector_type(4)));

// Problem constants
static constexpr int Hdim = 1024;
static constexpr int Vdim = 128;
static constexpr int Bdim = 64;
static constexpr int Sdim = 512;

// Step-kernel geometry (proven R11 structure, sync machinery removed)
static constexpr int NB   = 8;     // batches per block (= per cluster)
static constexpr int NI   = 32;    // output columns per block
static constexpr int KCH  = 32;    // k elements per thread chunk
static constexpr int SL   = 1028;  // LDS h row stride in floats
static constexpr int NBLK = 256;   // blocks per step kernel (8 cl x 32 slices)

// ---------------- prep: pack U^T ----------------
// Up[s][k][il] = U[s*32+il][k]  (block s streams a contiguous [1024][32] slice)
__global__ void __launch_bounds__(256) pack_u_kernel(const float* __restrict__ U,
                                                     float* __restrict__ Up) {
  __shared__ float tile[32][257];
  const int s  = blockIdx.x;        // 0..31 (column-slice)
  const int k0 = blockIdx.y * 256;  // 0,256,512,768
  const int t  = threadIdx.x;
  #pragma unroll
  for (int r = 0; r < 32; ++r)
    tile[r][t] = U[(size_t)(s * 32 + r) * Hdim + k0 + t];
  __syncthreads();
  const size_t base = ((size_t)s * Hdim + k0) * 32;
  #pragma unroll
  for (int r2 = 0; r2 < 32; ++r2) {
    int g = r2 * 256 + t;           // g = k_rel*32 + il
    Up[base + g] = tile[g & 31][g >> 5];
  }
}

// ---------------- prep: W [1024][128] -> Wt [128][1024] ----------------
__global__ void transpose_w_kernel(const float* __restrict__ in, float* __restrict__ out) {
  __shared__ float tile[32][33];
  const int bx = blockIdx.x * 32;   // col base (vocab)
  const int by = blockIdx.y * 32;   // row base (hidden)
  const int tx = threadIdx.x, ty = threadIdx.y;  // 32 x 8
  #pragma unroll
  for (int dy = 0; dy < 32; dy += 8)
    tile[ty + dy][tx] = in[(size_t)(by + ty + dy) * Vdim + bx + tx];
  __syncthreads();
  #pragma unroll
  for (int dy = 0; dy < 32; dy += 8)
    out[(size_t)(bx + ty + dy) * Hdim + by + tx] = tile[tx][ty + dy];
}

// ---------------- one recurrence step (+ fused logits for step t-1) ----------------
// Plain cached loads/stores everywhere: cross-kernel visibility comes from the
// HSA dispatch-boundary release/acquire -- no custom sync, no asm, no atomics.
// t == 0:    h_0 = 0 (no read);  t == Sdim: logits only (no recurrence).
__global__ void __launch_bounds__(256) rnn_step_kernel(
    const float* __restrict__ Up,   // [32][1024][32] packed U^T
    const float* __restrict__ Wt,   // [V][H]
    const int*   __restrict__ X,    // [B][S]
    const float* __restrict__ lw,   // [V][H]
    const float* __restrict__ lb,   // [V]
    const float* __restrict__ hin,  // h_t   [B][H]  (unused when t==0)
    float* __restrict__ hout,       // h_{t+1} [B][H] (unused when t==Sdim)
    float* __restrict__ out,        // [B][S][V] logits
    int t)
{
  __shared__ float hsm[NB * SL];          // staged h_t slice (8 rows)
  __shared__ float part[4][NB][NI];       // per-wave recurrence partials
  __shared__ float partv[4][NB][4];       // per-wave logit partials

  const int tid  = threadIdx.x;
  const int blk  = blockIdx.x;
  const int cl   = blk >> 5;              // cluster 0..7
  const int s    = blk & 31;              // column-slice 0..31
  const int i0   = s * NI;                // global column base
  const int bg0  = cl * NB;               // global batch base
  const int kp   = tid >> 3;              // 0..31
  const int b    = tid & 7;               // 0..7
  const int w    = tid >> 6;              // wave 0..3
  const int lane = tid & 63;
  const float* Ublk = Up + (size_t)s * Hdim * NI;

  // ---- stage h_t into LDS (coalesced cached float4 loads) ----
  if (t == 0) {
    const f32x4 z = (f32x4){0.f, 0.f, 0.f, 0.f};
    #pragma unroll
    for (int r = 0; r < NB; ++r)
      *((f32x4*)&hsm[r * SL + tid * 4]) = z;
  } else {
    const f32x4* src = (const f32x4*)(hin + (size_t)bg0 * Hdim);
    #pragma unroll
    for (int r = 0; r < NB; ++r) {
      f32x4 v = src[r * (Hdim / 4) + tid];
      *((f32x4*)&hsm[r * SL + tid * 4]) = v;
    }
  }
  __syncthreads();

  // ---- recurrence partials: acc[i] = sum over k-chunk of U^T[k][i]*h[k] ----
  if (t < Sdim) {
    float acc[NI];
    #pragma unroll
    for (int i = 0; i < NI; ++i) acc[i] = 0.f;
    const float* hr = &hsm[b * SL + kp * KCH];
    const f32x4* ub = (const f32x4*)(Ublk + (size_t)kp * KCH * NI);
    #pragma unroll 4
    for (int j = 0; j < KCH; ++j) {
      int jj = (j + kp) & (KCH - 1);
      float hv = hr[jj];
      const f32x4* u = ub + (size_t)jj * (NI / 4);
      #pragma unroll
      for (int q = 0; q < NI / 4; ++q) {
        const f32x4 uq = u[q];
        acc[q * 4 + 0] += uq[0] * hv;
        acc[q * 4 + 1] += uq[1] * hv;
        acc[q * 4 + 2] += uq[2] * hv;
        acc[q * 4 + 3] += uq[3] * hv;
      }
    }
    #pragma unroll
    for (int i = 0; i < NI; ++i) {
      acc[i] += __shfl_xor(acc[i], 8, 64);
      acc[i] += __shfl_xor(acc[i], 16, 64);
      acc[i] += __shfl_xor(acc[i], 32, 64);
    }
    if ((lane & 56) == 0) {
      #pragma unroll
      for (int i = 0; i < NI; i += 4)
        *((f32x4*)&part[w][b][i]) = (f32x4){acc[i], acc[i + 1], acc[i + 2], acc[i + 3]};
    }
  }

  // ---- logit partials for step t-1 (h_t still in hsm) ----
  if (t > 0) {
    float a0 = 0.f, a1 = 0.f, a2 = 0.f, a3 = 0.f;
    const f32x4* lw0 = (const f32x4*)(lw + (size_t)(4 * s)     * Hdim + kp * KCH);
    const f32x4* lw1 = (const f32x4*)(lw + (size_t)(4 * s + 1) * Hdim + kp * KCH);
    const f32x4* lw2 = (const f32x4*)(lw + (size_t)(4 * s + 2) * Hdim + kp * KCH);
    const f32x4* lw3 = (const f32x4*)(lw + (size_t)(4 * s + 3) * Hdim + kp * KCH);
    const f32x4* hr4 = (const f32x4*)&hsm[b * SL + kp * KCH];
    #pragma unroll
    for (int j = 0; j < KCH / 4; ++j) {
      int jj = (j + kp) & (KCH / 4 - 1);
      f32x4 hv = hr4[jj];
      f32x4 q0 = lw0[jj], q1 = lw1[jj], q2 = lw2[jj], q3 = lw3[jj];
      #pragma unroll
      for (int e = 0; e < 4; ++e) {
        a0 += hv[e] * q0[e]; a1 += hv[e] * q1[e];
        a2 += hv[e] * q2[e]; a3 += hv[e] * q3[e];
      }
    }
    #pragma unroll
    for (int d = 8; d < 64; d <<= 1) {
      a0 += __shfl_xor(a0, d, 64); a1 += __shfl_xor(a1, d, 64);
      a2 += __shfl_xor(a2, d, 64); a3 += __shfl_xor(a3, d, 64);
    }
    if ((lane & 56) == 0)
      *((f32x4*)&partv[w][b][0]) = (f32x4){a0, a1, a2, a3};
  }
  __syncthreads();

  // ---- combine: h_{t+1} update ----
  if (t < Sdim) {
    const int b2 = tid >> 5, i2 = tid & 31;
    float v = part[0][b2][i2] + part[1][b2][i2] + part[2][b2][i2] + part[3][b2][i2];
    const int x = X[(bg0 + b2) * Sdim + t];
    v += Wt[(size_t)x * Hdim + i0 + i2];
    hout[(size_t)(bg0 + b2) * Hdim + i0 + i2] = tanhf(v);
  }

  // ---- combine: logits(t-1) write ----
  if (t > 0 && tid >= 128 && tid < 128 + 4 * NB) {
    const int q = tid - 128;
    const int bb = q >> 2, vv = q & 3;
    float lv = partv[0][bb][vv] + partv[1][bb][vv] + partv[2][bb][vv] + partv[3][bb][vv];
    lv += lb[4 * s + vv];
    out[((size_t)(bg0 + bb) * Sdim + (t - 1)) * Vdim + 4 * s + vv] = lv;
  }
}

// ---------------- in-place softmax over last dim (128) ----------------
__global__ void __launch_bounds__(256) softmax_kernel(float* __restrict__ out) {
  const int row = blockIdx.x * 4 + (threadIdx.x >> 6);  // one wave per row
  const int l = threadIdx.x & 63;
  float* rp = out + (size_t)row * Vdim;
  float2 v = *((const float2*)&rp[l * 2]);
  float m = fmaxf(v.x, v.y);
  #pragma unroll
  for (int d = 1; d < 64; d <<= 1) m = fmaxf(m, __shfl_xor(m, d, 64));
  float e0 = expf(v.x - m), e1 = expf(v.y - m);
  float ss = e0 + e1;
  #pragma unroll
  for (int d = 1; d < 64; d <<= 1) ss += __shfl_xor(ss, d, 64);
  const float inv = 1.f / ss;
  *((float2*)&rp[l * 2]) = make_float2(e0 * inv, e1 * inv);
}

extern "C" void kernel_launch(void* const* d_in, const int* in_sizes, int n_in,
                              void* d_out, int out_size, void* d_ws, size_t ws_size,
                              hipStream_t stream) {
  const int*   X  = (const int*)d_in[0];
  const float* U  = (const float*)d_in[1];
  const float* W  = (const float*)d_in[2];
  const float* lw = (const float*)d_in[3];
  const float* lb = (const float*)d_in[4];
  float* out = (float*)d_out;

  // workspace (floats): Up[1M] | Wt[128K] | h0[64K] | h1[64K]
  float* Up = (float*)d_ws;
  float* Wt = Up + (size_t)1024 * 1024;
  float* h0 = Wt + (size_t)128 * 1024;
  float* h1 = h0 + (size_t)64 * 1024;
  const size_t need = ((size_t)1024 * 1024 + 128 * 1024 + 2 * 64 * 1024) * 4;
  if (ws_size < need) return;

  hipLaunchKernelGGL(pack_u_kernel, dim3(32, 4), dim3(256), 0, stream, U, Up);
  hipLaunchKernelGGL(transpose_w_kernel, dim3(4, 32), dim3(32, 8), 0, stream, W, Wt);

  // 513 step kernels: t=0..511 do recurrence (+ logits t-1); t=512 logits only.
  // Cross-kernel h visibility is guaranteed by stream-ordered dispatch
  // boundaries (hardware release/acquire) -- no fences, no atomics anywhere.
  for (int t = 0; t <= Sdim; ++t) {
    const float* hin = (t & 1) ? h1 : h0;   // h_t
    float* hout      = (t & 1) ? h0 : h1;   // h_{t+1}
    hipLaunchKernelGGL(rnn_step_kernel, dim3(NBLK), dim3(256), 0, stream,
                       Up, Wt, X, lw, lb, hin, hout, out, t);
  }

  hipLaunchKernelGGL(softmax_kernel, dim3((Bdim * Sdim) / 4), dim3(256), 0, stream, out);
}